// Round 1
// baseline (271.879 us; speedup 1.0000x reference)
//
#include <hip/hip_runtime.h>

#define TAU 0.02f

constexpr int Bc = 8, Cc = 64, Hc = 256, Wc = 256;
constexpr int R  = 32;   // output rows per tile
constexpr int NR = 40;   // staged rows; 40*256*4 = 40960 B -> 4 blocks/CU

__device__ __forceinline__ void coordf(float g, float shift, int n,
                                       int& i0, int& i1, float& w) {
    // exact reference semantics
    float p = (g + shift + 1.0f) * (0.5f * (float)(n - 1));
    p = fminf(fmaxf(p, 0.0f), (float)(n - 1));
    float f = floorf(p);
    w  = p - f;
    i0 = (int)f;
    i1 = min(i0 + 1, n - 1);
}

// clamp-adjusted pair: taps always (m, m+1); weight 1.0 when i0 clamped to n-1.
__device__ __forceinline__ void coord_adj(float g, float shift, int n,
                                          int& m, float& w) {
    int i0, i1; float ww;
    coordf(g, shift, n, i0, i1, ww);
    const bool top = (i0 == n - 1);
    m = top ? n - 2 : i0;
    w = top ? 1.0f  : ww;
}

__device__ __forceinline__ float gy_of(int i) {
    return fmaf((float)i, 2.0f / 255.0f, -1.0f);   // validated rounds 2-4 (prev session)
}

__device__ __forceinline__ float rdlane_f(float v, int lane) {
    return __int_as_float(__builtin_amdgcn_readlane(__float_as_int(v), lane));
}

__global__ __launch_bounds__(256, 4) void remizov_sten(
    const float* __restrict__ x,
    const float* __restrict__ th_a,
    const float* __restrict__ th_bx,
    const float* __restrict__ th_by,
    const float* __restrict__ th_c,
    const float* __restrict__ base_gx,
    const float* __restrict__ base_gy,
    float* __restrict__ out)
{
    __shared__ float tile[NR * Wc];   // exactly 40 KB

    const int j  = threadIdx.x;
    const int i0 = blockIdx.x * R;
    const int c  = blockIdx.y;
    const int b  = blockIdx.z;

    // ---- per-channel constants ----
    const float a  = log1pf(expf(th_a[c]));   // softplus
    const float s  = sqrtf(a * TAU + 1e-8f);
    const float dx = th_bx[c] * TAU;
    const float dy = th_by[c] * TAU;
    const float tc = th_c[c]  * TAU;

    // ---- per-lane exact y metadata: lane (j&31) owns output row i0+(j&31) ----
    int   m_yc, m_yp, m_yn;
    float m_wc, m_wp, m_wn;
    {
        const float gyr = gy_of(i0 + (j & 31));
        coord_adj(gyr,      dy, Hc, m_yc, m_wc);
        coord_adj(gyr,  s + dy, Hc, m_yp, m_wp);
        coord_adj(gyr, -s + dy, Hc, m_yn, m_wn);
    }

    // ---- staged window (coord map monotone in i) ----
    int rlo = min(i0, min(min(__builtin_amdgcn_readlane(m_yc, 0),
                              __builtin_amdgcn_readlane(m_yp, 0)),
                              __builtin_amdgcn_readlane(m_yn, 0)));
    int rhi = max(i0 + R - 1, max(max(__builtin_amdgcn_readlane(m_yc, 31),
                                      __builtin_amdgcn_readlane(m_yp, 31)),
                                      __builtin_amdgcn_readlane(m_yn, 31)) + 1);
    const int nrows = rhi - rlo + 1;

    // ---- x metadata: row-invariant, clamp-adjusted contiguous pairs ----
    const float gxv = base_gx[j];
    int xp, xn, xc; float wxp, wxn, wxc;
    coord_adj(gxv,  s + dx, Wc, xp, wxp);
    coord_adj(gxv, -s + dx, Wc, xn, wxn);
    coord_adj(gxv,      dx, Wc, xc, wxc);

    const size_t plane = (size_t)(b * Cc + c) * (size_t)(Hc * Wc);
    float* __restrict__ dst = out + plane + (size_t)i0 * Wc + j;

    if (nrows > NR) {
        // ---- fallback: direct-global (shift > 4 px; ~10 sigma, never in practice) ----
        const float* __restrict__ P = x + plane;
        for (int r = 0; r < R; ++r) {
            const float gyr = gy_of(i0 + r);
            int yc, yp, yn; float wyc, wyp, wyn;
            coord_adj(gyr,      dy, Hc, yc, wyc);
            coord_adj(gyr,  s + dy, Hc, yp, wyp);
            coord_adj(gyr, -s + dy, Hc, yn, wyn);
            auto bilg = [&](int y0, float wy, int x0, float wx) -> float {
                const float* r0 = P + y0 * Wc;
                const float* r1 = r0 + Wc;
                float t0 = r0[x0] + wx * (r0[x0 + 1] - r0[x0]);
                float t1 = r1[x0] + wx * (r1[x0 + 1] - r1[x0]);
                return t0 + wy * (t1 - t0);
            };
            float v0 = bilg(yc, wyc, xp, wxp);
            float v1 = bilg(yc, wyc, xn, wxn);
            float v2 = bilg(yp, wyp, xc, wxc);
            float v3 = bilg(yn, wyn, xc, wxc);
            float xv = P[(i0 + r) * Wc + j];
            dst[r * Wc] = 0.25f * (v0 + v1 + v2 + v3) + tc * xv;
        }
        return;
    }

    // ---- stage contiguous row window: coalesced float4 copy ----
    {
        const float* __restrict__ src = x + plane + (size_t)rlo * Wc;
        const int total = nrows * Wc;
        for (int e = j * 4; e < total; e += 256 * 4) {
            *reinterpret_cast<float4*>(&tile[e]) =
                *reinterpret_cast<const float4*>(src + e);
        }
    }
    __syncthreads();

    // ---- uniform-stencil parameters from lane 16 ----
    const int acr = __builtin_amdgcn_readlane(m_yc, 16) - (i0 + 16);
    const int apr = __builtin_amdgcn_readlane(m_yp, 16) - (i0 + 16);
    const int anr = __builtin_amdgcn_readlane(m_yn, 16) - (i0 + 16);
    const float wc = rdlane_f(m_wc, 16);
    const float wp = rdlane_f(m_wp, 16);
    const float wn = rdlane_f(m_wn, 16);

    // per-row conformity mask (bit r = row i0+r conforms to the uniform stencil).
    // mask == full  =>  all stream reads lie in [rlo, rhi] by construction of rlo/rhi.
    unsigned int mask;
    {
        const int lane = j & 31;
        bool ok = (m_yc == i0 + lane + acr) &&
                  (m_yp == i0 + lane + apr) &&
                  (m_yn == i0 + lane + anr);
        mask = (unsigned int)__ballot(ok);   // lanes 32..63 mirror lanes 0..31
    }

    if (mask == 0xFFFFFFFFu) {
        // ================= fast uniform path =================
        // Three 2-register streams at runtime row offsets; no clamps, no 9-tap window.
        const int icp = (i0 + acr - rlo) * Wc + xp;   // Sc stream, xp tap pair
        const int icn = (i0 + acr - rlo) * Wc + xn;   // Sc stream, xn tap pair
        const int ipp = (i0 + apr - rlo) * Wc + xc;   // Wp stream
        const int inn = (i0 + anr - rlo) * Wc + xc;   // Wn stream
        const int ixx = (i0       - rlo) * Wc + j;    // own-value stream

        auto lerp2 = [&](int idx, float w) -> float {  // one ds_read2_b32 + sub + fma
            float t0 = tile[idx], t1 = tile[idx + 1];
            return t0 + w * (t1 - t0);
        };

        float Sc0 = lerp2(icp,      wxp) + lerp2(icn,      wxn);
        float Sc1 = lerp2(icp + Wc, wxp) + lerp2(icn + Wc, wxn);
        float Wp0 = lerp2(ipp,      wxc);
        float Wp1 = lerp2(ipp + Wc, wxc);
        float Wn0 = lerp2(inn,      wxc);
        float Wn1 = lerp2(inn + Wc, wxc);

#pragma unroll
        for (int r = 0; r < R; ++r) {
            float v01 = Sc0 + wc * (Sc1 - Sc0);
            float v2  = Wp0 + wp * (Wp1 - Wp0);
            float v3  = Wn0 + wn * (Wn1 - Wn0);
            float xv  = tile[ixx + r * Wc];
            dst[(size_t)(r << 8)] = 0.25f * (v01 + v2 + v3) + tc * xv;
            if (r < R - 1) {
                const int adv = (r + 2) * Wc;
                Sc0 = Sc1;
                Sc1 = lerp2(icp + adv, wxp) + lerp2(icn + adv, wxn);
                Wp0 = Wp1;
                Wp1 = lerp2(ipp + adv, wxc);
                Wn0 = Wn1;
                Wn1 = lerp2(inn + adv, wxc);
            }
        }
    } else {
        // ================= exact path (border tiles / rare floor flips) =================
        auto ldH = [&](int row, int xm, float wx) -> float {
            row = min(max(row, rlo), rhi);
            const int base = (row - rlo) << 8;
            float t0 = tile[base + xm], t1 = tile[base + xm + 1];
            return t0 + wx * (t1 - t0);
        };
        auto ldS = [&](int row) -> float {
            return ldH(row, xp, wxp) + ldH(row, xn, wxn);
        };
        const int xvbase = (i0 - rlo) * Wc + j;
        for (int r = 0; r < R; ++r) {
            const float gyr = gy_of(i0 + r);
            int yc, yp, yn; float wyc, wyp, wyn;
            coord_adj(gyr,      dy, Hc, yc, wyc);
            coord_adj(gyr,  s + dy, Hc, yp, wyp);
            coord_adj(gyr, -s + dy, Hc, yn, wyn);
            float v01 = (1.0f - wyc) * ldS(yc) + wyc * ldS(yc + 1);
            float v2  = (1.0f - wyp) * ldH(yp,     xc, wxc)
                      +         wyp  * ldH(yp + 1, xc, wxc);
            float v3  = (1.0f - wyn) * ldH(yn,     xc, wxc)
                      +         wyn  * ldH(yn + 1, xc, wxc);
            const float xv = tile[xvbase + (r << 8)];
            dst[(size_t)(r << 8)] = 0.25f * (v01 + v2 + v3) + tc * xv;
        }
    }
}

extern "C" void kernel_launch(void* const* d_in, const int* in_sizes, int n_in,
                              void* d_out, int out_size, void* d_ws, size_t ws_size,
                              hipStream_t stream)
{
    const float* x       = (const float*)d_in[0];
    const float* th_a    = (const float*)d_in[1];
    const float* th_bx   = (const float*)d_in[2];
    const float* th_by   = (const float*)d_in[3];
    const float* th_c    = (const float*)d_in[4];
    const float* base_gx = (const float*)d_in[5];
    const float* base_gy = (const float*)d_in[6];
    float* out = (float*)d_out;

    dim3 grid(Hc / R, Cc, Bc);
    dim3 block(Wc);
    remizov_sten<<<grid, block, 0, stream>>>(x, th_a, th_bx, th_by, th_c,
                                             base_gx, base_gy, out);
}

// Round 3
// 262.038 us; speedup vs baseline: 1.0376x; 1.0376x over previous
//
#include <hip/hip_runtime.h>

#define TAU 0.02f

constexpr int Bc = 8, Cc = 64, Hc = 256, Wc = 256;
constexpr int R  = 16;   // output rows per tile
constexpr int NR = 24;   // staged rows; 24*256*4 = 24576 B -> 6 blocks/CU (24 waves, 75%)

__device__ __forceinline__ void coordf(float g, float shift, int n,
                                       int& i0, int& i1, float& w) {
    // exact reference semantics
    float p = (g + shift + 1.0f) * (0.5f * (float)(n - 1));
    p = fminf(fmaxf(p, 0.0f), (float)(n - 1));
    float f = floorf(p);
    w  = p - f;
    i0 = (int)f;
    i1 = min(i0 + 1, n - 1);
}

// clamp-adjusted pair: taps always (m, m+1); weight 1.0 when i0 clamped to n-1.
__device__ __forceinline__ void coord_adj(float g, float shift, int n,
                                          int& m, float& w) {
    int i0, i1; float ww;
    coordf(g, shift, n, i0, i1, ww);
    const bool top = (i0 == n - 1);
    m = top ? n - 2 : i0;
    w = top ? 1.0f  : ww;
}

__device__ __forceinline__ float gy_of(int i) {
    return fmaf((float)i, 2.0f / 255.0f, -1.0f);   // validated rounds 2-4 (prev session)
}

__device__ __forceinline__ float rdlane_f(float v, int lane) {
    return __int_as_float(__builtin_amdgcn_readlane(__float_as_int(v), lane));
}

__global__ __launch_bounds__(256, 6) void remizov_sten(
    const float* __restrict__ x,
    const float* __restrict__ th_a,
    const float* __restrict__ th_bx,
    const float* __restrict__ th_by,
    const float* __restrict__ th_c,
    const float* __restrict__ base_gx,
    const float* __restrict__ base_gy,
    float* __restrict__ out)
{
    __shared__ float tile[NR * Wc];   // exactly 24 KB

    const int j  = threadIdx.x;
    const int i0 = blockIdx.x * R;
    const int c  = blockIdx.y;
    const int b  = blockIdx.z;

    // ---- per-channel constants ----
    const float a  = log1pf(expf(th_a[c]));   // softplus
    const float s  = sqrtf(a * TAU + 1e-8f);
    const float dx = th_bx[c] * TAU;
    const float dy = th_by[c] * TAU;
    const float tc = th_c[c]  * TAU;

    // ---- per-lane exact y metadata: lane (j&15) owns output row i0+(j&15) ----
    // (R=16: lanes mirror in groups of 16 across the 64-lane wave)
    const int lane16 = j & 15;
    int   m_yc, m_yp, m_yn;
    float m_wc, m_wp, m_wn;
    {
        const float gyr = gy_of(i0 + lane16);
        coord_adj(gyr,      dy, Hc, m_yc, m_wc);
        coord_adj(gyr,  s + dy, Hc, m_yp, m_wp);
        coord_adj(gyr, -s + dy, Hc, m_yn, m_wn);
    }

    // ---- staged window (coord map monotone in i) ----
    int rlo = min(i0, min(min(__builtin_amdgcn_readlane(m_yc, 0),
                              __builtin_amdgcn_readlane(m_yp, 0)),
                              __builtin_amdgcn_readlane(m_yn, 0)));
    int rhi = max(i0 + R - 1, max(max(__builtin_amdgcn_readlane(m_yc, 15),
                                      __builtin_amdgcn_readlane(m_yp, 15)),
                                      __builtin_amdgcn_readlane(m_yn, 15)) + 1);
    const int nrows = rhi - rlo + 1;

    // ---- x metadata: row-invariant, clamp-adjusted contiguous pairs ----
    const float gxv = base_gx[j];
    int xp, xn, xc; float wxp, wxn, wxc;
    coord_adj(gxv,  s + dx, Wc, xp, wxp);
    coord_adj(gxv, -s + dx, Wc, xn, wxn);
    coord_adj(gxv,      dx, Wc, xc, wxc);

    const size_t plane = (size_t)(b * Cc + c) * (size_t)(Hc * Wc);
    float* __restrict__ dst = out + plane + (size_t)i0 * Wc + j;

    if (nrows > NR) {
        // ---- fallback: direct-global (shift > 4 px; ~10 sigma, never in practice) ----
        const float* __restrict__ P = x + plane;
        for (int r = 0; r < R; ++r) {
            const float gyr = gy_of(i0 + r);
            int yc, yp, yn; float wyc, wyp, wyn;
            coord_adj(gyr,      dy, Hc, yc, wyc);
            coord_adj(gyr,  s + dy, Hc, yp, wyp);
            coord_adj(gyr, -s + dy, Hc, yn, wyn);
            auto bilg = [&](int y0, float wy, int x0, float wx) -> float {
                const float* r0 = P + y0 * Wc;
                const float* r1 = r0 + Wc;
                float t0 = r0[x0] + wx * (r0[x0 + 1] - r0[x0]);
                float t1 = r1[x0] + wx * (r1[x0 + 1] - r1[x0]);
                return t0 + wy * (t1 - t0);
            };
            float v0 = bilg(yc, wyc, xp, wxp);
            float v1 = bilg(yc, wyc, xn, wxn);
            float v2 = bilg(yp, wyp, xc, wxc);
            float v3 = bilg(yn, wyn, xc, wxc);
            float xv = P[(i0 + r) * Wc + j];
            dst[r * Wc] = 0.25f * (v0 + v1 + v2 + v3) + tc * xv;
        }
        return;
    }

    // ---- stage contiguous row window: coalesced float4 copy ----
    {
        const float* __restrict__ src = x + plane + (size_t)rlo * Wc;
        const int total = nrows * Wc;
        for (int e = j * 4; e < total; e += 256 * 4) {
            *reinterpret_cast<float4*>(&tile[e]) =
                *reinterpret_cast<const float4*>(src + e);
        }
    }
    __syncthreads();

    // ---- uniform-stencil parameters from lane 8 ----
    const int acr = __builtin_amdgcn_readlane(m_yc, 8) - (i0 + 8);
    const int apr = __builtin_amdgcn_readlane(m_yp, 8) - (i0 + 8);
    const int anr = __builtin_amdgcn_readlane(m_yn, 8) - (i0 + 8);
    const float wc = rdlane_f(m_wc, 8);
    const float wp = rdlane_f(m_wp, 8);
    const float wn = rdlane_f(m_wn, 8);

    // conformity: every row of the tile matches the uniform stencil.
    // all-conforming => all stream reads lie in [rlo, rhi] by construction.
    bool ok = (m_yc == i0 + lane16 + acr) &&
              (m_yp == i0 + lane16 + apr) &&
              (m_yn == i0 + lane16 + anr);
    const unsigned long long mask = __ballot(ok);

    if (mask == 0xFFFFFFFFFFFFFFFFull) {
        // ================= fast uniform path =================
        // Three 2-register streams at runtime row offsets; no clamps.
        const int icp = (i0 + acr - rlo) * Wc + xp;   // Sc stream, xp tap pair
        const int icn = (i0 + acr - rlo) * Wc + xn;   // Sc stream, xn tap pair
        const int ipp = (i0 + apr - rlo) * Wc + xc;   // Wp stream
        const int inn = (i0 + anr - rlo) * Wc + xc;   // Wn stream
        const int ixx = (i0       - rlo) * Wc + j;    // own-value stream

        auto lerp2 = [&](int idx, float w) -> float {  // one ds_read2_b32 + sub + fma
            float t0 = tile[idx], t1 = tile[idx + 1];
            return t0 + w * (t1 - t0);
        };

        float Sc0 = lerp2(icp,      wxp) + lerp2(icn,      wxn);
        float Sc1 = lerp2(icp + Wc, wxp) + lerp2(icn + Wc, wxn);
        float Wp0 = lerp2(ipp,      wxc);
        float Wp1 = lerp2(ipp + Wc, wxc);
        float Wn0 = lerp2(inn,      wxc);
        float Wn1 = lerp2(inn + Wc, wxc);

#pragma unroll
        for (int r = 0; r < R; ++r) {
            float v01 = Sc0 + wc * (Sc1 - Sc0);
            float v2  = Wp0 + wp * (Wp1 - Wp0);
            float v3  = Wn0 + wn * (Wn1 - Wn0);
            float xv  = tile[ixx + r * Wc];
            dst[(size_t)(r << 8)] = 0.25f * (v01 + v2 + v3) + tc * xv;
            if (r < R - 1) {
                const int adv = (r + 2) * Wc;
                Sc0 = Sc1;
                Sc1 = lerp2(icp + adv, wxp) + lerp2(icn + adv, wxn);
                Wp0 = Wp1;
                Wp1 = lerp2(ipp + adv, wxc);
                Wn0 = Wn1;
                Wn1 = lerp2(inn + adv, wxc);
            }
        }
    } else {
        // ================= exact path (border tiles / rare floor flips) =================
        auto ldH = [&](int row, int xm, float wx) -> float {
            row = min(max(row, rlo), rhi);
            const int base = (row - rlo) << 8;
            float t0 = tile[base + xm], t1 = tile[base + xm + 1];
            return t0 + wx * (t1 - t0);
        };
        auto ldS = [&](int row) -> float {
            return ldH(row, xp, wxp) + ldH(row, xn, wxn);
        };
        const int xvbase = (i0 - rlo) * Wc + j;
        for (int r = 0; r < R; ++r) {
            const float gyr = gy_of(i0 + r);
            int yc, yp, yn; float wyc, wyp, wyn;
            coord_adj(gyr,      dy, Hc, yc, wyc);
            coord_adj(gyr,  s + dy, Hc, yp, wyp);
            coord_adj(gyr, -s + dy, Hc, yn, wyn);
            float v01 = (1.0f - wyc) * ldS(yc) + wyc * ldS(yc + 1);
            float v2  = (1.0f - wyp) * ldH(yp,     xc, wxc)
                      +         wyp  * ldH(yp + 1, xc, wxc);
            float v3  = (1.0f - wyn) * ldH(yn,     xc, wxc)
                      +         wyn  * ldH(yn + 1, xc, wxc);
            const float xv = tile[xvbase + (r << 8)];
            dst[(size_t)(r << 8)] = 0.25f * (v01 + v2 + v3) + tc * xv;
        }
    }
}

extern "C" void kernel_launch(void* const* d_in, const int* in_sizes, int n_in,
                              void* d_out, int out_size, void* d_ws, size_t ws_size,
                              hipStream_t stream)
{
    const float* x       = (const float*)d_in[0];
    const float* th_a    = (const float*)d_in[1];
    const float* th_bx   = (const float*)d_in[2];
    const float* th_by   = (const float*)d_in[3];
    const float* th_c    = (const float*)d_in[4];
    const float* base_gx = (const float*)d_in[5];
    const float* base_gy = (const float*)d_in[6];
    float* out = (float*)d_out;

    dim3 grid(Hc / R, Cc, Bc);
    dim3 block(Wc);
    remizov_sten<<<grid, block, 0, stream>>>(x, th_a, th_bx, th_by, th_c,
                                             base_gx, base_gy, out);
}